// Round 2
// baseline (179.869 us; speedup 1.0000x reference)
//
#include <hip/hip_runtime.h>

// CharGRU2: 2-layer GRU (reset_after=true) + dense + softmax, fp32.
// B=2048, T=128, V=256, H=20, L=15.
//
// Layout (round 2): 3 batch elements per 64-lane wave, 20 lanes per batch
// group. Lane (20*g + j) owns ALL THREE gate columns (j, j+20, j+40) of
// batch group g — so gate math needs no cross-lane gathers at all, and the
// per-step h broadcast is 20 ds_bpermute per layer serving all 3 batches.
// Weights live in ~180 VGPRs per lane (launch_bounds(256,1) -> 512-reg budget;
// we only have 683 waves for 1024 SIMDs, so 1 wave/SIMD occupancy is free).

#define BB 2048
#define TT 128
#define HH 20
#define LL 15
#define H3 60

__device__ __forceinline__ float bperm(int byteaddr, float v) {
    return __int_as_float(__builtin_amdgcn_ds_bpermute(byteaddr, __float_as_int(v)));
}
__device__ __forceinline__ float fast_rcp(float x) { return __builtin_amdgcn_rcpf(x); }
__device__ __forceinline__ float sigm(float x) { return fast_rcp(1.f + __expf(-x)); }
__device__ __forceinline__ float tanh_f(float x) { return 1.f - 2.f * fast_rcp(1.f + __expf(2.f * x)); }

extern "C" __global__ __launch_bounds__(256, 1)
void gru2_kernel(const int* __restrict__ x, const float* __restrict__ W0,
                 const float* __restrict__ U0, const float* __restrict__ b0i,
                 const float* __restrict__ b0r, const float* __restrict__ W1,
                 const float* __restrict__ U1, const float* __restrict__ b1i,
                 const float* __restrict__ b1r, const float* __restrict__ Wd,
                 const float* __restrict__ bd, float* __restrict__ out)
{
    const int lane = threadIdx.x & 63;
    const int wv = blockIdx.x * 4 + (threadIdx.x >> 6);
    const int g = (lane >= 40) ? 2 : ((lane >= 20) ? 1 : 0); // batch group 0..2
    int j = lane - g * 20; if (j > 19) j = 19;               // lanes 60..63 mirror (2,19)
    const int b  = wv * 3 + g;
    const int bl = (b < BB) ? b : (BB - 1);                  // clamped for loads
    const int gb4 = g * 80;                                  // group base, byte addr

    const int c0 = j, c1 = j + 20, c2 = j + 40;              // this lane's gate columns

    // ---- weight columns into VGPRs (once) ----
    float u0z[HH], u0r[HH], u0h[HH], w1z[HH], w1r[HH], w1h[HH], u1z[HH], u1r[HH], u1h[HH];
#pragma unroll
    for (int k = 0; k < HH; ++k) {
        u0z[k] = U0[k * H3 + c0]; u0r[k] = U0[k * H3 + c1]; u0h[k] = U0[k * H3 + c2];
        w1z[k] = W1[k * H3 + c0]; w1r[k] = W1[k * H3 + c1]; w1h[k] = W1[k * H3 + c2];
        u1z[k] = U1[k * H3 + c0]; u1r[k] = U1[k * H3 + c1]; u1h[k] = U1[k * H3 + c2];
    }
    const float bi0z = b0i[c0], bi0r = b0i[c1], bi0h = b0i[c2];
    const float br0z = b0r[c0], br0r = b0r[c1], br0h = b0r[c2];
    const float bi1z = b1i[c0], bi1r = b1i[c1], bi1h = b1i[c2];
    const float br1z = b1r[c0], br1r = b1r[c1], br1h = b1r[c2];

    const int* xrow = x + bl * TT;

    float h0own = 0.f, h1own = 0.f;   // this lane's unit of h0/h1 for its batch
    float vh0[HH];                    // replicated h0 (per group) for matvecs
#pragma unroll
    for (int k = 0; k < HH; ++k) vh0[k] = 0.f;

    // ---- software pipeline init: tokens t=0..2, W0 rows t=0,1 ----
    const int tok0  = xrow[0];
    const int tok1  = xrow[1];
    int tokn2 = xrow[2];                                   // token for t+2
    float xz  = W0[tok0 * H3 + c0] + bi0z;                 // xw for t (ready)
    float xr_ = W0[tok0 * H3 + c1] + bi0r;
    float xh_ = W0[tok0 * H3 + c2] + bi0h;
    float nz  = W0[tok1 * H3 + c0];                        // raw W0 row for t+1
    float nr  = W0[tok1 * H3 + c1];
    float nh  = W0[tok1 * H3 + c2];

    for (int t = 0; t < TT; ++t) {
        // prefetch: W0 row for t+2 (token already here), token for t+3
        const int t3 = (t + 3 < TT) ? (t + 3) : (TT - 1);
        const float pz = W0[tokn2 * H3 + c0];
        const float pr = W0[tokn2 * H3 + c1];
        const float ph = W0[tokn2 * H3 + c2];
        const int tokn3 = xrow[t3];

        // ---- layer 0: rec0 = h0 @ U0 + b0r (3 indep 20-deep chains) ----
        float rz = br0z, rr = br0r, rh = br0h;
#pragma unroll
        for (int k = 0; k < HH; ++k) {
            rz = fmaf(vh0[k], u0z[k], rz);
            rr = fmaf(vh0[k], u0r[k], rr);
            rh = fmaf(vh0[k], u0h[k], rh);
        }
        const float z  = sigm(xz + rz);
        const float r  = sigm(xr_ + rr);
        const float hh = tanh_f(xh_ + r * rh);
        h0own = fmaf(z, h0own - hh, hh);                   // z*h + (1-z)*hh

        // rebuild replicated h0 (20 bperm serve all 3 batches)
#pragma unroll
        for (int k = 0; k < HH; ++k) vh0[k] = bperm(gb4 + (k << 2), h0own);

        // ---- layer 1: rec1 fused with h1 broadcast (covers vh0 bperm latency) ----
        float r1z = br1z, r1r = br1r, r1h = br1h;
#pragma unroll
        for (int k = 0; k < HH; ++k) {
            const float t1 = bperm(gb4 + (k << 2), h1own); // pre-update h1
            r1z = fmaf(t1, u1z[k], r1z);
            r1r = fmaf(t1, u1r[k], r1r);
            r1h = fmaf(t1, u1h[k], r1h);
        }
        float x1z = bi1z, x1r = bi1r, x1h = bi1h;
#pragma unroll
        for (int k = 0; k < HH; ++k) {
            x1z = fmaf(vh0[k], w1z[k], x1z);
            x1r = fmaf(vh0[k], w1r[k], x1r);
            x1h = fmaf(vh0[k], w1h[k], x1h);
        }
        const float z1  = sigm(x1z + r1z);
        const float r1  = sigm(x1r + r1r);
        const float hh1 = tanh_f(x1h + r1 * r1h);
        h1own = fmaf(z1, h1own - hh1, hh1);

        // rotate pipeline: t+1 becomes current, t+2 raw row staged
        xz = nz + bi0z; xr_ = nr + bi0r; xh_ = nh + bi0h;
        nz = pz; nr = pr; nh = ph;
        tokn2 = tokn3;
    }

    // ---- dense (h1 @ Wd + bd) + softmax within each 20-lane group ----
    const int jc = (j < LL) ? j : (LL - 1);
    float acc = bd[jc];
#pragma unroll
    for (int k = 0; k < HH; ++k) {
        const float t1 = bperm(gb4 + (k << 2), h1own);
        acc = fmaf(t1, Wd[k * LL + jc], acc);
    }
    float m = acc;
#pragma unroll
    for (int i = 0; i < LL; ++i) m = fmaxf(m, bperm(gb4 + (i << 2), acc));
    const float e = __expf(acc - m);
    float s = 0.f;
#pragma unroll
    for (int i = 0; i < LL; ++i) s += bperm(gb4 + (i << 2), e);
    const float p = e * fast_rcp(s);

    if (j < LL && b < BB) out[b * LL + j] = p;
}

extern "C" void kernel_launch(void* const* d_in, const int* in_sizes, int n_in,
                              void* d_out, int out_size, void* d_ws, size_t ws_size,
                              hipStream_t stream) {
    const int*   x   = (const int*)  d_in[0];
    const float* W0  = (const float*)d_in[1];
    const float* U0  = (const float*)d_in[2];
    const float* b0i = (const float*)d_in[3];
    const float* b0r = (const float*)d_in[4];
    const float* W1  = (const float*)d_in[5];
    const float* U1  = (const float*)d_in[6];
    const float* b1i = (const float*)d_in[7];
    const float* b1r = (const float*)d_in[8];
    const float* Wd  = (const float*)d_in[9];
    const float* bd  = (const float*)d_in[10];
    // d_in[11] = drop_rate (identity), unused
    float* out = (float*)d_out;

    // 3 batches/wave, 4 waves/block -> 12 batches/block; ceil(2048/12) = 171 blocks
    dim3 grid((BB + 11) / 12), block(256);
    hipLaunchKernelGGL(gru2_kernel, grid, block, 0, stream,
                       x, W0, U0, b0i, b0r, W1, U1, b1i, b1r, Wd, bd, out);
}

// Round 3
// 173.634 us; speedup vs baseline: 1.0359x; 1.0359x over previous
//
#include <hip/hip_runtime.h>

// CharGRU2: 2-layer GRU (reset_after=true) + dense + softmax, fp32.
// B=2048, T=128, V=256, H=20, L=15.
//
// Round 3: 3 batches/wave (20 lanes each; lane owns gate-cols j, j+20, j+40 of
// its batch). Two fixes over round 2, which was VMEM-latency-bound because the
// compiler sank the weight loads back into the t-loop (VGPR_Count=136 < 180
// needed; no scratch => reload, not spill):
//   1. asm volatile("" : "+v") pins every weight value in a VGPR — opaque def,
//      cannot be rematerialized as a load. K-loop runs load-free.
//   2. Weights/h packed as float2 along k; __builtin_elementwise_fma coaxes
//      v_pk_fma_f32 (2 fp32 MACs/inst): 180 -> 90 matvec insts per step.
//   3. 1 wave per block (683 blocks): round 2's 171x4-wave blocks left 85 CUs
//      completely idle (<=1 block/CU). Now every CU carries 2-3 waves.

#define BB 2048
#define TT 128
#define HH 20
#define HP 10   // k-pairs
#define LL 15
#define H3 60

typedef float v2f __attribute__((ext_vector_type(2)));

__device__ __forceinline__ float bperm(int byteaddr, float v) {
    return __int_as_float(__builtin_amdgcn_ds_bpermute(byteaddr, __float_as_int(v)));
}
__device__ __forceinline__ float fast_rcp(float x) { return __builtin_amdgcn_rcpf(x); }
__device__ __forceinline__ float sigm(float x) { return fast_rcp(1.f + __expf(-x)); }
__device__ __forceinline__ float tanh_f(float x) { return 1.f - 2.f * fast_rcp(1.f + __expf(2.f * x)); }
#define PIN(v) asm volatile("" : "+v"(v))

extern "C" __global__ __launch_bounds__(64, 1)
void gru2_kernel(const int* __restrict__ x, const float* __restrict__ W0,
                 const float* __restrict__ U0, const float* __restrict__ b0i,
                 const float* __restrict__ b0r, const float* __restrict__ W1,
                 const float* __restrict__ U1, const float* __restrict__ b1i,
                 const float* __restrict__ b1r, const float* __restrict__ Wd,
                 const float* __restrict__ bd, float* __restrict__ out)
{
    const int lane = threadIdx.x;                            // one wave per block
    const int g = (lane >= 40) ? 2 : ((lane >= 20) ? 1 : 0); // batch group 0..2
    int j = lane - g * 20; if (j > 19) j = 19;               // lanes 60..63 mirror
    const int b  = blockIdx.x * 3 + g;
    const int bl = (b < BB) ? b : (BB - 1);
    const int gb4 = g * 80;                                  // group base byte addr

    const int c0 = j, c1 = j + 20, c2 = j + 40;

    // ---- weight columns, packed in k-pairs, pinned into VGPRs ----
    v2f u0z[HP], u0r[HP], u0h[HP], w1z[HP], w1r[HP], w1h[HP], u1z[HP], u1r[HP], u1h[HP];
#pragma unroll
    for (int p = 0; p < HP; ++p) {
        const int k0 = 2 * p * H3, k1 = (2 * p + 1) * H3;
        u0z[p] = v2f{U0[k0 + c0], U0[k1 + c0]};
        u0r[p] = v2f{U0[k0 + c1], U0[k1 + c1]};
        u0h[p] = v2f{U0[k0 + c2], U0[k1 + c2]};
        w1z[p] = v2f{W1[k0 + c0], W1[k1 + c0]};
        w1r[p] = v2f{W1[k0 + c1], W1[k1 + c1]};
        w1h[p] = v2f{W1[k0 + c2], W1[k1 + c2]};
        u1z[p] = v2f{U1[k0 + c0], U1[k1 + c0]};
        u1r[p] = v2f{U1[k0 + c1], U1[k1 + c1]};
        u1h[p] = v2f{U1[k0 + c2], U1[k1 + c2]};
    }
#pragma unroll
    for (int p = 0; p < HP; ++p) {
        PIN(u0z[p]); PIN(u0r[p]); PIN(u0h[p]);
        PIN(w1z[p]); PIN(w1r[p]); PIN(w1h[p]);
        PIN(u1z[p]); PIN(u1r[p]); PIN(u1h[p]);
    }
    float bi0z = b0i[c0], bi0r = b0i[c1], bi0h = b0i[c2];
    float br0z = b0r[c0], br0r = b0r[c1], br0h = b0r[c2];
    float bi1z = b1i[c0], bi1r = b1i[c1], bi1h = b1i[c2];
    float br1z = b1r[c0], br1r = b1r[c1], br1h = b1r[c2];
    PIN(bi0z); PIN(bi0r); PIN(bi0h); PIN(br0z); PIN(br0r); PIN(br0h);
    PIN(bi1z); PIN(bi1r); PIN(bi1h); PIN(br1z); PIN(br1r); PIN(br1h);

    const int* xrow = x + bl * TT;

    float h0own = 0.f, h1own = 0.f;
    v2f vh0[HP], vh1[HP];
#pragma unroll
    for (int p = 0; p < HP; ++p) { vh0[p] = v2f{0.f, 0.f}; vh1[p] = v2f{0.f, 0.f}; }

    // ---- software pipeline: tokens t=0..2 staged, W0 rows t=0,1 ----
    const int tok0 = xrow[0];
    const int tok1 = xrow[1];
    int tokn2 = xrow[2];
    float xz  = W0[tok0 * H3 + c0] + bi0z;
    float xr_ = W0[tok0 * H3 + c1] + bi0r;
    float xh_ = W0[tok0 * H3 + c2] + bi0h;
    float nz  = W0[tok1 * H3 + c0];
    float nr  = W0[tok1 * H3 + c1];
    float nh  = W0[tok1 * H3 + c2];

    for (int t = 0; t < TT; ++t) {
        // prefetch W0 row for t+2, token for t+3
        const int t3 = (t + 3 < TT) ? (t + 3) : (TT - 1);
        const float pz = W0[tokn2 * H3 + c0];
        const float pr = W0[tokn2 * H3 + c1];
        const float ph = W0[tokn2 * H3 + c2];
        const int tokn3 = xrow[t3];

        // ---- layer 0: rec0 = h0 @ U0 + b0r (3 chains x 10 pk_fma) ----
        v2f az = v2f{br0z, 0.f}, ar = v2f{br0r, 0.f}, ah = v2f{br0h, 0.f};
#pragma unroll
        for (int p = 0; p < HP; ++p) {
            az = __builtin_elementwise_fma(vh0[p], u0z[p], az);
            ar = __builtin_elementwise_fma(vh0[p], u0r[p], ar);
            ah = __builtin_elementwise_fma(vh0[p], u0h[p], ah);
        }
        const float z  = sigm(xz + az.x + az.y);
        const float r  = sigm(xr_ + ar.x + ar.y);
        const float hh = tanh_f(xh_ + r * (ah.x + ah.y));
        h0own = fmaf(z, h0own - hh, hh);

        // rebuild replicated h0 (serves all 3 batches; overlaps with rec1 below)
#pragma unroll
        for (int p = 0; p < HP; ++p) {
            v2f v; v.x = bperm(gb4 + 8 * p, h0own); v.y = bperm(gb4 + 8 * p + 4, h0own);
            vh0[p] = v;
        }

        // ---- layer 1: rec1 = h1 @ U1 + b1r (vh1 from end of prev step) ----
        v2f bz = v2f{br1z, 0.f}, br = v2f{br1r, 0.f}, bh = v2f{br1h, 0.f};
#pragma unroll
        for (int p = 0; p < HP; ++p) {
            bz = __builtin_elementwise_fma(vh1[p], u1z[p], bz);
            br = __builtin_elementwise_fma(vh1[p], u1r[p], br);
            bh = __builtin_elementwise_fma(vh1[p], u1h[p], bh);
        }
        // xw1 = h0new @ W1 + b1i
        v2f cz = v2f{bi1z, 0.f}, cr = v2f{bi1r, 0.f}, ch = v2f{bi1h, 0.f};
#pragma unroll
        for (int p = 0; p < HP; ++p) {
            cz = __builtin_elementwise_fma(vh0[p], w1z[p], cz);
            cr = __builtin_elementwise_fma(vh0[p], w1r[p], cr);
            ch = __builtin_elementwise_fma(vh0[p], w1h[p], ch);
        }
        const float z1  = sigm(cz.x + cz.y + bz.x + bz.y);
        const float r1  = sigm(cr.x + cr.y + br.x + br.y);
        const float hh1 = tanh_f(ch.x + ch.y + r1 * (bh.x + bh.y));
        h1own = fmaf(z1, h1own - hh1, hh1);

        // rebuild replicated h1 for next step's rec1
#pragma unroll
        for (int p = 0; p < HP; ++p) {
            v2f v; v.x = bperm(gb4 + 8 * p, h1own); v.y = bperm(gb4 + 8 * p + 4, h1own);
            vh1[p] = v;
        }

        // rotate x-pipeline
        xz = nz + bi0z; xr_ = nr + bi0r; xh_ = nh + bi0h;
        nz = pz; nr = pr; nh = ph;
        tokn2 = tokn3;
    }

    // ---- dense (h1 @ Wd + bd) + softmax within each 20-lane group ----
    const int jc = (j < LL) ? j : (LL - 1);
    float acc = bd[jc];
#pragma unroll
    for (int k = 0; k < HH; ++k) {
        const float t1 = bperm(gb4 + (k << 2), h1own);
        acc = fmaf(t1, Wd[k * LL + jc], acc);
    }
    float m = acc;
#pragma unroll
    for (int i = 0; i < LL; ++i) m = fmaxf(m, bperm(gb4 + (i << 2), acc));
    const float e = __expf(acc - m);
    float s = 0.f;
#pragma unroll
    for (int i = 0; i < LL; ++i) s += bperm(gb4 + (i << 2), e);
    const float p = e * fast_rcp(s);

    if (j < LL && b < BB) out[b * LL + j] = p;
}

extern "C" void kernel_launch(void* const* d_in, const int* in_sizes, int n_in,
                              void* d_out, int out_size, void* d_ws, size_t ws_size,
                              hipStream_t stream) {
    const int*   x   = (const int*)  d_in[0];
    const float* W0  = (const float*)d_in[1];
    const float* U0  = (const float*)d_in[2];
    const float* b0i = (const float*)d_in[3];
    const float* b0r = (const float*)d_in[4];
    const float* W1  = (const float*)d_in[5];
    const float* U1  = (const float*)d_in[6];
    const float* b1i = (const float*)d_in[7];
    const float* b1r = (const float*)d_in[8];
    const float* Wd  = (const float*)d_in[9];
    const float* bd  = (const float*)d_in[10];
    // d_in[11] = drop_rate (identity), unused
    float* out = (float*)d_out;

    // 3 batches per wave, ONE wave per block: 683 blocks spread over 256 CUs
    // (2-3 waves/CU on distinct SIMDs) — round 2's 4-wave blocks idled 85 CUs.
    dim3 grid((BB + 2) / 3), block(64);
    hipLaunchKernelGGL(gru2_kernel, grid, block, 0, stream,
                       x, W0, U0, b0i, b0r, W1, U1, b1i, b1r, Wd, bd, out);
}

// Round 4
// 160.854 us; speedup vs baseline: 1.1182x; 1.0795x over previous
//
#include <hip/hip_runtime.h>

// CharGRU2: 2-layer GRU (reset_after=true) + dense + softmax, fp32.
// B=2048, T=128, V=256, H=20, L=15.
//
// Round 4: back to the round-1 decomposition (1 batch/wave, lane c owns gate
// column c of the 3H=60-wide gate vectors; h broadcast via v_readlane->SGPR
// fma operand), with the two diagnosed bugs fixed:
//   1. __launch_bounds__(256, 2): round 1's bare launch_bounds(256) made the
//      compiler target high occupancy -> VGPR_Count=40 -> it reloaded all 60
//      weight floats from L1/L2 EVERY timestep (in-loop VMEM + addr VALU).
//      We supply exactly 2 waves/SIMD (2048 waves), so request exactly that:
//      256-VGPR budget, weights stay resident (~105 live regs). PIN insures
//      against rematerialization.
//   2. Role-based gates: lane's own column IS its gate (z on lanes 0-19,
//      r on 20-39, h~ on 40-59). No pre-gathers: 2 bperm/layer (was 4) and
//      2 exp + 2 rcp/layer (was 3+3).
// Round 2/3's 3-batch/180-reg design lost to the register allocator twice
// (spill-after-PIN at VGPR=144, 1/3 SIMDs idle) — abandoned.

#define BB 2048
#define TT 128
#define HH 20
#define LL 15
#define H3 60

__device__ __forceinline__ float bclane(float v, int k) {
    return __int_as_float(__builtin_amdgcn_readlane(__float_as_int(v), k));
}
__device__ __forceinline__ float bperm(int byteaddr, float v) {
    return __int_as_float(__builtin_amdgcn_ds_bpermute(byteaddr, __float_as_int(v)));
}
__device__ __forceinline__ float fast_rcp(float x) { return __builtin_amdgcn_rcpf(x); }
__device__ __forceinline__ float sigm(float x) { return fast_rcp(1.f + __expf(-x)); }
__device__ __forceinline__ float tanh_f(float x) { return 1.f - 2.f * fast_rcp(1.f + __expf(2.f * x)); }
#define PIN(v) asm volatile("" : "+v"(v))

extern "C" __global__ __launch_bounds__(256, 2)
void gru2_kernel(const int* __restrict__ x, const float* __restrict__ W0,
                 const float* __restrict__ U0, const float* __restrict__ b0i,
                 const float* __restrict__ b0r, const float* __restrict__ W1,
                 const float* __restrict__ U1, const float* __restrict__ b1i,
                 const float* __restrict__ b1r, const float* __restrict__ Wd,
                 const float* __restrict__ bd, float* __restrict__ out)
{
    const int lane = threadIdx.x & 63;
    const int b = blockIdx.x * 4 + (threadIdx.x >> 6);   // batch = wave id
    const int c = lane < H3 ? lane : H3 - 1;             // own gate column

    // ---- weight columns into VGPRs, once, pinned ----
    float u0c[HH], w1c[HH], u1c[HH];
#pragma unroll
    for (int k = 0; k < HH; ++k) {
        u0c[k] = U0[k * H3 + c];
        w1c[k] = W1[k * H3 + c];
        u1c[k] = U1[k * H3 + c];
    }
#pragma unroll
    for (int k = 0; k < HH; ++k) { PIN(u0c[k]); PIN(w1c[k]); PIN(u1c[k]); }
    float bi0 = b0i[c], br0 = b0r[c], bi1 = b1i[c], br1 = b1r[c];
    PIN(bi0); PIN(br0); PIN(bi1); PIN(br1);

    // ---- all 128 tokens of this sequence into 2 VGPRs ----
    const int* xrow = x + b * TT;
    const int tokA = xrow[lane];
    const int tokB = xrow[64 + lane];

    // bperm addresses for the two gate hops:
    //  h-lane (c in 40..59) pulls r of its unit from lane c-20
    //  z-lane (c in 0..19)  pulls hh of its unit from lane c+40
    const int aR = ((lane - 20) & 63) << 2;
    const int aH = ((lane + 40) & 63) << 2;

    float h0 = 0.f, h1 = 0.f;   // valid on lanes 0..19 (unit j on lane j)

    // ---- 2-deep W0 pipeline: row t ready, row t+1 raw, token t+2 staged ----
    const int tok0 = __builtin_amdgcn_readlane(tokA, 0);
    const int tok1 = __builtin_amdgcn_readlane(tokA, 1);
    int tokn2 = __builtin_amdgcn_readlane(tokA, 2);
    float xw_cur = W0[tok0 * H3 + c] + bi0;
    float xw_nxt = W0[tok1 * H3 + c];

    for (int t = 0; t < TT; ++t) {
        // prefetch: W0 row for t+2 (token staged), token for t+3
        const int t3 = (t + 3 < TT) ? (t + 3) : (TT - 1);
        const float xw_pf = W0[tokn2 * H3 + c];
        const int tokn3 = __builtin_amdgcn_readlane(t3 < 64 ? tokA : tokB, t3 & 63);

        // ---- layer 0 ----
        float rec0 = br0;
#pragma unroll
        for (int k = 0; k < HH; ++k)
            rec0 = fmaf(bclane(h0, k), u0c[k], rec0);
        const float sg0 = sigm(xw_cur + rec0);       // z on lanes 0-19, r on 20-39
        const float rv0 = bperm(aR, sg0);            // r_j  -> lane j+40
        const float th0 = tanh_f(xw_cur + rv0 * rec0); // h~ on lanes 40-59
        const float hh0 = bperm(aH, th0);            // hh_j -> lane j
        h0 = fmaf(sg0, h0 - hh0, hh0);               // z*h + (1-z)*hh (lanes 0-19)

        // ---- layer 1: xw1 = h0@W1 + bi1 ; rec1 = h1@U1 + br1 ----
        float xw1 = bi1, rec1 = br1;
#pragma unroll
        for (int k = 0; k < HH; ++k) {
            xw1  = fmaf(bclane(h0, k), w1c[k], xw1);
            rec1 = fmaf(bclane(h1, k), u1c[k], rec1);
        }
        const float sg1 = sigm(xw1 + rec1);
        const float rv1 = bperm(aR, sg1);
        const float th1 = tanh_f(xw1 + rv1 * rec1);
        const float hh1 = bperm(aH, th1);
        h1 = fmaf(sg1, h1 - hh1, hh1);

        // rotate W0 pipeline
        xw_cur = xw_nxt + bi0;
        xw_nxt = xw_pf;
        tokn2 = tokn3;
    }

    // ---- dense (h1 @ Wd + bd) + softmax, lanes 0..14 ----
    const int l = lane < LL ? lane : LL - 1;
    float acc = bd[l];
#pragma unroll
    for (int k = 0; k < HH; ++k)
        acc = fmaf(bclane(h1, k), Wd[k * LL + l], acc);

    float m = acc;
#pragma unroll
    for (int i = 0; i < LL; ++i) m = fmaxf(m, bclane(acc, i));
    const float e = __expf(acc - m);
    float s = 0.f;
#pragma unroll
    for (int i = 0; i < LL; ++i) s += bclane(e, i);
    const float p = e * fast_rcp(s);

    if (lane < LL) out[b * LL + lane] = p;
}

extern "C" void kernel_launch(void* const* d_in, const int* in_sizes, int n_in,
                              void* d_out, int out_size, void* d_ws, size_t ws_size,
                              hipStream_t stream) {
    const int*   x   = (const int*)  d_in[0];
    const float* W0  = (const float*)d_in[1];
    const float* U0  = (const float*)d_in[2];
    const float* b0i = (const float*)d_in[3];
    const float* b0r = (const float*)d_in[4];
    const float* W1  = (const float*)d_in[5];
    const float* U1  = (const float*)d_in[6];
    const float* b1i = (const float*)d_in[7];
    const float* b1r = (const float*)d_in[8];
    const float* Wd  = (const float*)d_in[9];
    const float* bd  = (const float*)d_in[10];
    // d_in[11] = drop_rate (identity), unused
    float* out = (float*)d_out;

    // 1 batch/wave, 4 waves/block -> 512 blocks = 2 blocks/CU = 2 waves/SIMD,
    // matching __launch_bounds__(256, 2).
    dim3 grid(BB / 4), block(256);
    hipLaunchKernelGGL(gru2_kernel, grid, block, 0, stream,
                       x, W0, U0, b0i, b0r, W1, U1, b1i, b1r, Wd, bd, out);
}

// Round 5
// 157.776 us; speedup vs baseline: 1.1400x; 1.0195x over previous
//
#include <hip/hip_runtime.h>

// CharGRU2: 2-layer GRU (reset_after=true) + dense + softmax, fp32.
// B=2048, T=128, V=256, H=20, L=15.
//
// Round 5: identical decomposition to round 4 (1 batch/wave, lane c owns gate
// column c; h broadcast via v_readlane -> SGPR fma operand; role-based gates,
// 2 bperm + 2 exp + 2 rcp per layer). ONE change:
//
//   __attribute__((amdgpu_waves_per_eu(2, 2)))
//
// Diagnosis from rounds 1/4 (both VGPR_Count=40): __launch_bounds__' 2nd arg
// only sets the MIN of amdgpu-waves-per-eu; the allocator still TARGETS the
// max of the range (~10 waves/EU -> ~48-reg goal) and spills the pinned
// weights to scratch, reloading them in-loop through L1. That makes the
// kernel L1-throughput-bound: 8 waves/CU x 60 dwords/step x ~4cyc = 1920
// cyc/CU-step, matching the measured 1753 cyc/step. Capping max waves/EU at 2
// (we launch exactly 2048 waves = 2/SIMD) raises the allocator's budget to
// 256 VGPRs so the ~75 live values (60 weights + state) stay resident.

#define BB 2048
#define TT 128
#define HH 20
#define LL 15
#define H3 60

__device__ __forceinline__ float bclane(float v, int k) {
    return __int_as_float(__builtin_amdgcn_readlane(__float_as_int(v), k));
}
__device__ __forceinline__ float bperm(int byteaddr, float v) {
    return __int_as_float(__builtin_amdgcn_ds_bpermute(byteaddr, __float_as_int(v)));
}
__device__ __forceinline__ float fast_rcp(float x) { return __builtin_amdgcn_rcpf(x); }
__device__ __forceinline__ float sigm(float x) { return fast_rcp(1.f + __expf(-x)); }
__device__ __forceinline__ float tanh_f(float x) { return 1.f - 2.f * fast_rcp(1.f + __expf(2.f * x)); }
#define PIN(v) asm volatile("" : "+v"(v))

extern "C" __global__ __launch_bounds__(256)
__attribute__((amdgpu_waves_per_eu(2, 2)))
void gru2_kernel(const int* __restrict__ x, const float* __restrict__ W0,
                 const float* __restrict__ U0, const float* __restrict__ b0i,
                 const float* __restrict__ b0r, const float* __restrict__ W1,
                 const float* __restrict__ U1, const float* __restrict__ b1i,
                 const float* __restrict__ b1r, const float* __restrict__ Wd,
                 const float* __restrict__ bd, float* __restrict__ out)
{
    const int lane = threadIdx.x & 63;
    const int b = blockIdx.x * 4 + (threadIdx.x >> 6);   // batch = wave id
    const int c = lane < H3 ? lane : H3 - 1;             // own gate column

    // ---- weight columns into VGPRs, once, pinned ----
    float u0c[HH], w1c[HH], u1c[HH];
#pragma unroll
    for (int k = 0; k < HH; ++k) {
        u0c[k] = U0[k * H3 + c];
        w1c[k] = W1[k * H3 + c];
        u1c[k] = U1[k * H3 + c];
    }
#pragma unroll
    for (int k = 0; k < HH; ++k) { PIN(u0c[k]); PIN(w1c[k]); PIN(u1c[k]); }
    float bi0 = b0i[c], br0 = b0r[c], bi1 = b1i[c], br1 = b1r[c];
    PIN(bi0); PIN(br0); PIN(bi1); PIN(br1);

    // ---- all 128 tokens of this sequence into 2 VGPRs ----
    const int* xrow = x + b * TT;
    const int tokA = xrow[lane];
    const int tokB = xrow[64 + lane];

    // bperm addresses for the two gate hops:
    //  h-lane (c in 40..59) pulls r of its unit from lane c-20
    //  z-lane (c in 0..19)  pulls hh of its unit from lane c+40
    const int aR = ((lane - 20) & 63) << 2;
    const int aH = ((lane + 40) & 63) << 2;

    float h0 = 0.f, h1 = 0.f;   // valid on lanes 0..19 (unit j on lane j)

    // ---- 2-deep W0 pipeline: row t ready, row t+1 raw, token t+2 staged ----
    const int tok0 = __builtin_amdgcn_readlane(tokA, 0);
    const int tok1 = __builtin_amdgcn_readlane(tokA, 1);
    int tokn2 = __builtin_amdgcn_readlane(tokA, 2);
    float xw_cur = W0[tok0 * H3 + c] + bi0;
    float xw_nxt = W0[tok1 * H3 + c];

    for (int t = 0; t < TT; ++t) {
        // prefetch: W0 row for t+2 (token staged), token for t+3
        const int t3 = (t + 3 < TT) ? (t + 3) : (TT - 1);
        const float xw_pf = W0[tokn2 * H3 + c];
        const int tokn3 = __builtin_amdgcn_readlane(t3 < 64 ? tokA : tokB, t3 & 63);

        // ---- layer 0 ----
        float rec0 = br0;
#pragma unroll
        for (int k = 0; k < HH; ++k)
            rec0 = fmaf(bclane(h0, k), u0c[k], rec0);
        const float sg0 = sigm(xw_cur + rec0);         // z on lanes 0-19, r on 20-39
        const float rv0 = bperm(aR, sg0);              // r_j  -> lane j+40
        const float th0 = tanh_f(xw_cur + rv0 * rec0); // h~ on lanes 40-59
        const float hh0 = bperm(aH, th0);              // hh_j -> lane j
        h0 = fmaf(sg0, h0 - hh0, hh0);                 // z*h + (1-z)*hh (lanes 0-19)

        // ---- layer 1: xw1 = h0@W1 + bi1 ; rec1 = h1@U1 + br1 ----
        float xw1 = bi1, rec1 = br1;
#pragma unroll
        for (int k = 0; k < HH; ++k) {
            xw1  = fmaf(bclane(h0, k), w1c[k], xw1);
            rec1 = fmaf(bclane(h1, k), u1c[k], rec1);
        }
        const float sg1 = sigm(xw1 + rec1);
        const float rv1 = bperm(aR, sg1);
        const float th1 = tanh_f(xw1 + rv1 * rec1);
        const float hh1 = bperm(aH, th1);
        h1 = fmaf(sg1, h1 - hh1, hh1);

        // rotate W0 pipeline
        xw_cur = xw_nxt + bi0;
        xw_nxt = xw_pf;
        tokn2 = tokn3;
    }

    // ---- dense (h1 @ Wd + bd) + softmax, lanes 0..14 ----
    const int l = lane < LL ? lane : LL - 1;
    float acc = bd[l];
#pragma unroll
    for (int k = 0; k < HH; ++k)
        acc = fmaf(bclane(h1, k), Wd[k * LL + l], acc);

    float m = acc;
#pragma unroll
    for (int i = 0; i < LL; ++i) m = fmaxf(m, bclane(acc, i));
    const float e = __expf(acc - m);
    float s = 0.f;
#pragma unroll
    for (int i = 0; i < LL; ++i) s += bclane(e, i);
    const float p = e * fast_rcp(s);

    if (lane < LL) out[b * LL + lane] = p;
}

extern "C" void kernel_launch(void* const* d_in, const int* in_sizes, int n_in,
                              void* d_out, int out_size, void* d_ws, size_t ws_size,
                              hipStream_t stream) {
    const int*   x   = (const int*)  d_in[0];
    const float* W0  = (const float*)d_in[1];
    const float* U0  = (const float*)d_in[2];
    const float* b0i = (const float*)d_in[3];
    const float* b0r = (const float*)d_in[4];
    const float* W1  = (const float*)d_in[5];
    const float* U1  = (const float*)d_in[6];
    const float* b1i = (const float*)d_in[7];
    const float* b1r = (const float*)d_in[8];
    const float* Wd  = (const float*)d_in[9];
    const float* bd  = (const float*)d_in[10];
    // d_in[11] = drop_rate (identity), unused
    float* out = (float*)d_out;

    // 1 batch/wave, 4 waves/block -> 512 blocks = 2 blocks/CU = 2 waves/SIMD,
    // matching amdgpu_waves_per_eu(2,2).
    dim3 grid(BB / 4), block(256);
    hipLaunchKernelGGL(gru2_kernel, grid, block, 0, stream,
                       x, W0, U0, b0i, b0r, W1, U1, b1i, b1r, Wd, bd, out);
}

// Round 6
// 150.231 us; speedup vs baseline: 1.1973x; 1.0502x over previous
//
#include <hip/hip_runtime.h>

// CharGRU2: 2-layer GRU (reset_after=true) + dense + softmax, fp32.
// B=2048, T=128, V=256, H=20, L=15.
//
// Round 6: same decomposition as R5 (1 batch/wave, lane c owns gate column c,
// h broadcast via v_readlane->SGPR fma operand, amdgpu_waves_per_eu(2,2)).
// R5 proved weights are register-resident (VGPR=88) yet time didn't move ->
// bottleneck is the ~600 cyc/step stall residue, dominated by TWO serial
// ds_bpermute levels per layer (~120 cyc each, m117) in the gate path.
//
// Restructure: h-home moves to lanes 20..39 (the r-columns). For unit j
// (lane 20+j): r = sigm(xr+rr) fully LOCAL; z needs (xz,rz) from lane j;
// h~ needs (xh,rh) from lane 40+j. All gathers depend only on (xw, rec) and
// issue in PARALLEL -> exactly ONE serial bperm level per layer (was two).
// Also: matvec accumulator chains split in two 10-deep halves (dep chain
// 80->~45 cyc), and t-loop unrolled 2x so the scheduler overlaps layer-1
// gates with the next step's layer-0 matvec.

#define BB 2048
#define TT 128
#define HH 20
#define LL 15
#define H3 60

__device__ __forceinline__ float bclane(float v, int k) {
    return __int_as_float(__builtin_amdgcn_readlane(__float_as_int(v), k));
}
__device__ __forceinline__ float bperm(int byteaddr, float v) {
    return __int_as_float(__builtin_amdgcn_ds_bpermute(byteaddr, __float_as_int(v)));
}
__device__ __forceinline__ float fast_rcp(float x) { return __builtin_amdgcn_rcpf(x); }
__device__ __forceinline__ float sigm(float x) { return fast_rcp(1.f + __expf(-x)); }
__device__ __forceinline__ float tanh_f(float x) { return 1.f - 2.f * fast_rcp(1.f + __expf(2.f * x)); }
#define PIN(v) asm volatile("" : "+v"(v))

extern "C" __global__ __launch_bounds__(256)
__attribute__((amdgpu_waves_per_eu(2, 2)))
void gru2_kernel(const int* __restrict__ x, const float* __restrict__ W0,
                 const float* __restrict__ U0, const float* __restrict__ b0i,
                 const float* __restrict__ b0r, const float* __restrict__ W1,
                 const float* __restrict__ U1, const float* __restrict__ b1i,
                 const float* __restrict__ b1r, const float* __restrict__ Wd,
                 const float* __restrict__ bd, float* __restrict__ out)
{
    const int lane = threadIdx.x & 63;
    const int b = blockIdx.x * 4 + (threadIdx.x >> 6);   // batch = wave id
    const int c = lane < H3 ? lane : H3 - 1;             // own gate column

    // ---- weight columns into VGPRs, once ----
    float u0c[HH], w1c[HH], u1c[HH];
#pragma unroll
    for (int k = 0; k < HH; ++k) {
        u0c[k] = U0[k * H3 + c];
        w1c[k] = W1[k * H3 + c];
        u1c[k] = U1[k * H3 + c];
    }
#pragma unroll
    for (int k = 0; k < HH; ++k) { PIN(u0c[k]); PIN(w1c[k]); PIN(u1c[k]); }
    float bi0 = b0i[c], br0 = b0r[c], bi1 = b1i[c], br1 = b1r[c];
    PIN(bi0); PIN(br0); PIN(bi1); PIN(br1);

    // ---- all 128 tokens of this sequence into 2 VGPRs ----
    const int* xrow = x + b * TT;
    const int tokA = xrow[lane];
    const int tokB = xrow[64 + lane];

    // bperm byte addrs for the gate lanes (20..39 meaningful):
    //  aZ: lane 20+j pulls from lane j     (xz_j, rz_j)
    //  aH: lane 20+j pulls from lane 40+j  (xh_j, rh_j)
    const int aZ = ((lane - 20) & 63) << 2;
    const int aH = ((lane + 20) & 63) << 2;

    float h0 = 0.f, h1 = 0.f;   // valid on lanes 20..39 (unit j at lane 20+j)

    // ---- 2-deep W0 pipeline: row t ready, row t+1 raw, token t+2 staged ----
    const int tok0 = __builtin_amdgcn_readlane(tokA, 0);
    const int tok1 = __builtin_amdgcn_readlane(tokA, 1);
    int tokn2 = __builtin_amdgcn_readlane(tokA, 2);
    float xw_cur = W0[tok0 * H3 + c] + bi0;
    float xw_nxt = W0[tok1 * H3 + c];

#pragma unroll 2
    for (int t = 0; t < TT; ++t) {
        // prefetch: W0 row for t+2 (token staged), token for t+3
        const int t3 = (t + 3 < TT) ? (t + 3) : (TT - 1);
        const float xw_pf = W0[tokn2 * H3 + c];
        const int tokn3 = __builtin_amdgcn_readlane(t3 < 64 ? tokA : tokB, t3 & 63);

        // off-critical-path gathers of the input-gate parts (xw ready at top)
        const float xz0 = bperm(aZ, xw_cur);   // xz_j -> lane 20+j
        const float xh0 = bperm(aH, xw_cur);   // xh_j -> lane 20+j

        // ---- layer 0 matvec: rec0 = h0 @ U0 + b0r, two 10-deep chains ----
        float r0a = br0, r0b = 0.f;
#pragma unroll
        for (int k = 0; k < 10; ++k)
            r0a = fmaf(bclane(h0, 20 + k), u0c[k], r0a);
#pragma unroll
        for (int k = 10; k < HH; ++k)
            r0b = fmaf(bclane(h0, 20 + k), u0c[k], r0b);
        const float rec0 = r0a + r0b;

        // ONE serial bperm level: rz, rh (parallel, both from rec0)
        const float rz0 = bperm(aZ, rec0);
        const float rh0 = bperm(aH, rec0);
        // gates, all local on lanes 20..39
        const float z0  = sigm(xz0 + rz0);
        const float r0  = sigm(xw_cur + rec0);         // xr + rr are local
        const float hh0 = tanh_f(xh0 + r0 * rh0);
        h0 = fmaf(z0, h0 - hh0, hh0);

        // ---- layer 1: xw1 = h0new @ W1 + bi1 ; rec1 = h1old @ U1 + br1 ----
        float xa = bi1, xb = 0.f, ra = br1, rb = 0.f;
#pragma unroll
        for (int k = 0; k < 10; ++k) {
            xa = fmaf(bclane(h0, 20 + k), w1c[k], xa);
            ra = fmaf(bclane(h1, 20 + k), u1c[k], ra);
        }
#pragma unroll
        for (int k = 10; k < HH; ++k) {
            xb = fmaf(bclane(h0, 20 + k), w1c[k], xb);
            rb = fmaf(bclane(h1, 20 + k), u1c[k], rb);
        }
        const float xw1 = xa + xb, rec1 = ra + rb;

        // ONE serial bperm level: all four gathers parallel
        const float xz1 = bperm(aZ, xw1);
        const float xh1 = bperm(aH, xw1);
        const float rz1 = bperm(aZ, rec1);
        const float rh1 = bperm(aH, rec1);
        const float z1  = sigm(xz1 + rz1);
        const float r1  = sigm(xw1 + rec1);
        const float hh1 = tanh_f(xh1 + r1 * rh1);
        h1 = fmaf(z1, h1 - hh1, hh1);

        // rotate W0 pipeline
        xw_cur = xw_nxt + bi0;
        xw_nxt = xw_pf;
        tokn2 = tokn3;
    }

    // ---- dense (h1 @ Wd + bd) + softmax, lanes 0..14 ----
    const int l = lane < LL ? lane : LL - 1;
    float acc = bd[l];
#pragma unroll
    for (int k = 0; k < HH; ++k)
        acc = fmaf(bclane(h1, 20 + k), Wd[k * LL + l], acc);

    float m = acc;
#pragma unroll
    for (int i = 0; i < LL; ++i) m = fmaxf(m, bclane(acc, i));
    const float e = __expf(acc - m);
    float s = 0.f;
#pragma unroll
    for (int i = 0; i < LL; ++i) s += bclane(e, i);
    const float p = e * fast_rcp(s);

    if (lane < LL) out[b * LL + lane] = p;
}

extern "C" void kernel_launch(void* const* d_in, const int* in_sizes, int n_in,
                              void* d_out, int out_size, void* d_ws, size_t ws_size,
                              hipStream_t stream) {
    const int*   x   = (const int*)  d_in[0];
    const float* W0  = (const float*)d_in[1];
    const float* U0  = (const float*)d_in[2];
    const float* b0i = (const float*)d_in[3];
    const float* b0r = (const float*)d_in[4];
    const float* W1  = (const float*)d_in[5];
    const float* U1  = (const float*)d_in[6];
    const float* b1i = (const float*)d_in[7];
    const float* b1r = (const float*)d_in[8];
    const float* Wd  = (const float*)d_in[9];
    const float* bd  = (const float*)d_in[10];
    // d_in[11] = drop_rate (identity), unused
    float* out = (float*)d_out;

    // 1 batch/wave, 4 waves/block -> 512 blocks = 2 blocks/CU = 2 waves/SIMD.
    dim3 grid(BB / 4), block(256);
    hipLaunchKernelGGL(gru2_kernel, grid, block, 0, stream,
                       x, W0, U0, b0i, b0r, W1, U1, b1i, b1r, Wd, bd, out);
}

// Round 7
// 148.303 us; speedup vs baseline: 1.2128x; 1.0130x over previous
//
#include <hip/hip_runtime.h>

// CharGRU2: 2-layer GRU (reset_after=true) + dense + softmax, fp32.
// B=2048, T=128, V=256, H=20, L=15.
//
// Round 7: R6 layout (1 batch/wave, lane c owns gate column c, 2 waves/SIMD,
// amdgpu_waves_per_eu(2,2)) with POST-ACTIVATION gathers:
//   * h home = lanes 40..59 (the h~ columns).
//   * One sigm(xw+rec) instruction yields z on lanes 0-19 AND r on lanes
//     20-39 (gate pre-activations are lane-local in this layout).
//   * tanh argument is lane-local on 40..59 (xh_j, rh_j are col 40+j).
//   * Only cross-lane traffic: pull post-activation r_j (lane 20+j) and z_j
//     (lane j) to lane 40+j -> 2 bperms/layer (R6: 4), both parallel off sg
//     -> still ONE serial bperm level per layer.
//   * Per layer: 1 sigm + 1 tanh (R6: 3 transcendental pairs).
//   * All v_readlane broadcasts batched ahead of the FMA chains so the
//     VALU->SGPR->VALU hazards overlap instead of serializing per pair.

#define BB 2048
#define TT 128
#define HH 20
#define LL 15
#define H3 60

__device__ __forceinline__ float bclane(float v, int k) {
    return __int_as_float(__builtin_amdgcn_readlane(__float_as_int(v), k));
}
__device__ __forceinline__ float bperm(int byteaddr, float v) {
    return __int_as_float(__builtin_amdgcn_ds_bpermute(byteaddr, __float_as_int(v)));
}
__device__ __forceinline__ float fast_rcp(float x) { return __builtin_amdgcn_rcpf(x); }
__device__ __forceinline__ float sigm(float x) { return fast_rcp(1.f + __expf(-x)); }
__device__ __forceinline__ float tanh_f(float x) { return 1.f - 2.f * fast_rcp(1.f + __expf(2.f * x)); }
#define PIN(v) asm volatile("" : "+v"(v))

extern "C" __global__ __launch_bounds__(256)
__attribute__((amdgpu_waves_per_eu(2, 2)))
void gru2_kernel(const int* __restrict__ x, const float* __restrict__ W0,
                 const float* __restrict__ U0, const float* __restrict__ b0i,
                 const float* __restrict__ b0r, const float* __restrict__ W1,
                 const float* __restrict__ U1, const float* __restrict__ b1i,
                 const float* __restrict__ b1r, const float* __restrict__ Wd,
                 const float* __restrict__ bd, float* __restrict__ out)
{
    const int lane = threadIdx.x & 63;
    const int b = blockIdx.x * 4 + (threadIdx.x >> 6);   // batch = wave id
    const int c = lane < H3 ? lane : H3 - 1;             // own gate column

    // ---- weight columns into VGPRs, once ----
    float u0c[HH], w1c[HH], u1c[HH];
#pragma unroll
    for (int k = 0; k < HH; ++k) {
        u0c[k] = U0[k * H3 + c];
        w1c[k] = W1[k * H3 + c];
        u1c[k] = U1[k * H3 + c];
    }
#pragma unroll
    for (int k = 0; k < HH; ++k) { PIN(u0c[k]); PIN(w1c[k]); PIN(u1c[k]); }
    float bi0 = b0i[c], br0 = b0r[c], bi1 = b1i[c], br1 = b1r[c];
    PIN(bi0); PIN(br0); PIN(bi1); PIN(br1);

    // ---- all 128 tokens of this sequence into 2 VGPRs ----
    const int* xrow = x + b * TT;
    const int tokA = xrow[lane];
    const int tokB = xrow[64 + lane];

    // bperm byte addrs (meaningful on lanes 40..59):
    //  aR: lane 40+j pulls r_j from lane 20+j
    //  aZ: lane 40+j pulls z_j from lane j
    const int aR = ((lane - 20) & 63) << 2;
    const int aZ = ((lane - 40) & 63) << 2;

    float h0 = 0.f, h1 = 0.f;   // home: lanes 40..59 (unit j at lane 40+j)

    // ---- 2-deep W0 pipeline: row t ready, row t+1 raw, token t+2 staged ----
    const int tok0 = __builtin_amdgcn_readlane(tokA, 0);
    const int tok1 = __builtin_amdgcn_readlane(tokA, 1);
    int tokn2 = __builtin_amdgcn_readlane(tokA, 2);
    float xw_cur = W0[tok0 * H3 + c] + bi0;
    float xw_nxt = W0[tok1 * H3 + c];

#pragma unroll 2
    for (int t = 0; t < TT; ++t) {
        // prefetch: W0 row for t+2 (token staged), token for t+3
        const int t3 = (t + 3 < TT) ? (t + 3) : (TT - 1);
        const float xw_pf = W0[tokn2 * H3 + c];
        const int tokn3 = __builtin_amdgcn_readlane(t3 < 64 ? tokA : tokB, t3 & 63);

        // ---- layer 0 matvec: rec0 = h0 @ U0 + b0r ----
        // batch ALL readlanes first (hazards overlap), then two 10-deep chains
        float hb0[HH];
#pragma unroll
        for (int k = 0; k < HH; ++k) hb0[k] = bclane(h0, 40 + k);
        float a0 = br0, a1 = 0.f;
#pragma unroll
        for (int k = 0; k < 10; ++k) a0 = fmaf(hb0[k], u0c[k], a0);
#pragma unroll
        for (int k = 10; k < HH; ++k) a1 = fmaf(hb0[k], u0c[k], a1);
        const float rec0 = a0 + a1;

        // one sigm serves z (lanes 0-19) and r (lanes 20-39); tanh local 40-59
        const float sg0 = sigm(xw_cur + rec0);
        const float rv0 = bperm(aR, sg0);            // r_j -> lane 40+j
        const float zv0 = bperm(aZ, sg0);            // z_j -> lane 40+j
        const float hh0 = tanh_f(xw_cur + rv0 * rec0); // xh_j + r_j*rh_j
        h0 = fmaf(zv0, h0 - hh0, hh0);               // on lanes 40..59

        // ---- layer 1: xw1 = h0new @ W1 + bi1 ; rec1 = h1old @ U1 + br1 ----
        float hc0[HH], hc1[HH];
#pragma unroll
        for (int k = 0; k < HH; ++k) { hc0[k] = bclane(h0, 40 + k); hc1[k] = bclane(h1, 40 + k); }
        float xa = bi1, xb = 0.f, ra = br1, rb = 0.f;
#pragma unroll
        for (int k = 0; k < 10; ++k) {
            xa = fmaf(hc0[k], w1c[k], xa);
            ra = fmaf(hc1[k], u1c[k], ra);
        }
#pragma unroll
        for (int k = 10; k < HH; ++k) {
            xb = fmaf(hc0[k], w1c[k], xb);
            rb = fmaf(hc1[k], u1c[k], rb);
        }
        const float xw1 = xa + xb, rec1 = ra + rb;

        const float sg1 = sigm(xw1 + rec1);
        const float rv1 = bperm(aR, sg1);
        const float zv1 = bperm(aZ, sg1);
        const float hh1 = tanh_f(xw1 + rv1 * rec1);
        h1 = fmaf(zv1, h1 - hh1, hh1);

        // rotate W0 pipeline
        xw_cur = xw_nxt + bi0;
        xw_nxt = xw_pf;
        tokn2 = tokn3;
    }

    // ---- dense (h1 @ Wd + bd) + softmax, lanes 0..14 ----
    const int l = lane < LL ? lane : LL - 1;
    float acc = bd[l];
#pragma unroll
    for (int k = 0; k < HH; ++k)
        acc = fmaf(bclane(h1, 40 + k), Wd[k * LL + l], acc);

    float m = acc;
#pragma unroll
    for (int i = 0; i < LL; ++i) m = fmaxf(m, bclane(acc, i));
    const float e = __expf(acc - m);
    float s = 0.f;
#pragma unroll
    for (int i = 0; i < LL; ++i) s += bclane(e, i);
    const float p = e * fast_rcp(s);

    if (lane < LL) out[b * LL + lane] = p;
}

extern "C" void kernel_launch(void* const* d_in, const int* in_sizes, int n_in,
                              void* d_out, int out_size, void* d_ws, size_t ws_size,
                              hipStream_t stream) {
    const int*   x   = (const int*)  d_in[0];
    const float* W0  = (const float*)d_in[1];
    const float* U0  = (const float*)d_in[2];
    const float* b0i = (const float*)d_in[3];
    const float* b0r = (const float*)d_in[4];
    const float* W1  = (const float*)d_in[5];
    const float* U1  = (const float*)d_in[6];
    const float* b1i = (const float*)d_in[7];
    const float* b1r = (const float*)d_in[8];
    const float* Wd  = (const float*)d_in[9];
    const float* bd  = (const float*)d_in[10];
    // d_in[11] = drop_rate (identity), unused
    float* out = (float*)d_out;

    // 1 batch/wave, 4 waves/block -> 512 blocks = 2 blocks/CU = 2 waves/SIMD.
    dim3 grid(BB / 4), block(256);
    hipLaunchKernelGGL(gru2_kernel, grid, block, 0, stream,
                       x, W0, U0, b0i, b0r, W1, U1, b1i, b1r, Wd, bd, out);
}

// Round 8
// 143.016 us; speedup vs baseline: 1.2577x; 1.0370x over previous
//
#include <hip/hip_runtime.h>

// CharGRU2: 2-layer GRU (reset_after=true) + dense + softmax, fp32.
// B=2048, T=128, V=256, H=20, L=15.
//
// Round 8: R7 layout (1 batch/wave, lane c owns gate column c, h home on
// lanes 40..59, post-activation gathers: 1 sigm + 1 tanh + 2 parallel bperm
// per layer, 2 waves/SIMD, amdgpu_waves_per_eu(2,2)).
//
// R7 diagnosis: ~520 issue-cyc/wave-step vs ~300 of real math -> the 60
// v_readlane broadcasts/step (VALU->SGPR->VALU hazards) are the dominant
// issue cost. This round replaces broadcasts for the two U-matvecs:
//   * h0/h1 staged in per-wave LDS (20 floats each, written once per step).
//     rec0 (next step) and rec1 (this step) read h via 5x ds_read_b128
//     BROADCAST (all lanes same address, conflict-free): 40 readlanes -> 10 DS.
//   * b128 delivers (h_2p, h_2p+1) pairs -> v_pk_fma_f32 against pair-packed
//     weight columns: even/odd-k partial sums. 40 fma -> 20 pk_fma.
//   * xw1 = h0_new @ W1 keeps readlane+fma (h0_new needed immediately;
//     readlane latency < LDS write->read round trip). Its LDS write for the
//     next step is off the critical path.
// No __syncthreads needed: LDS traffic is wave-private (in-order DS pipe).

#define BB 2048
#define TT 128
#define HH 20
#define LL 15
#define H3 60

typedef float v2f __attribute__((ext_vector_type(2)));

__device__ __forceinline__ float bclane(float v, int k) {
    return __int_as_float(__builtin_amdgcn_readlane(__float_as_int(v), k));
}
__device__ __forceinline__ float bperm(int byteaddr, float v) {
    return __int_as_float(__builtin_amdgcn_ds_bpermute(byteaddr, __float_as_int(v)));
}
__device__ __forceinline__ float fast_rcp(float x) { return __builtin_amdgcn_rcpf(x); }
__device__ __forceinline__ float sigm(float x) { return fast_rcp(1.f + __expf(-x)); }
__device__ __forceinline__ float tanh_f(float x) { return 1.f - 2.f * fast_rcp(1.f + __expf(2.f * x)); }
#define PIN(v) asm volatile("" : "+v"(v))

extern "C" __global__ __launch_bounds__(256)
__attribute__((amdgpu_waves_per_eu(2, 2)))
void gru2_kernel(const int* __restrict__ x, const float* __restrict__ W0,
                 const float* __restrict__ U0, const float* __restrict__ b0i,
                 const float* __restrict__ b0r, const float* __restrict__ W1,
                 const float* __restrict__ U1, const float* __restrict__ b1i,
                 const float* __restrict__ b1r, const float* __restrict__ Wd,
                 const float* __restrict__ bd, float* __restrict__ out)
{
    const int lane = threadIdx.x & 63;
    const int w = threadIdx.x >> 6;                      // wave in block
    const int b = blockIdx.x * 4 + w;                    // batch = wave id
    const int c = lane < H3 ? lane : H3 - 1;             // own gate column

    // per-wave LDS staging for h0/h1 (16B aligned chunks: 24-float stride)
    __shared__ __align__(16) float hbuf[4][2][24];
    float* h0buf = &hbuf[w][0][0];
    float* h1buf = &hbuf[w][1][0];
    if (lane >= 40 && lane < H3) { h0buf[lane - 40] = 0.f; h1buf[lane - 40] = 0.f; }

    // ---- weight columns into VGPRs, once; U0/U1 pair-packed along k ----
    v2f u0p[HH / 2], u1p[HH / 2];
    float w1c[HH];
#pragma unroll
    for (int p = 0; p < HH / 2; ++p) {
        u0p[p] = v2f{U0[(2 * p) * H3 + c], U0[(2 * p + 1) * H3 + c]};
        u1p[p] = v2f{U1[(2 * p) * H3 + c], U1[(2 * p + 1) * H3 + c]};
    }
#pragma unroll
    for (int k = 0; k < HH; ++k) w1c[k] = W1[k * H3 + c];
#pragma unroll
    for (int p = 0; p < HH / 2; ++p) { PIN(u0p[p]); PIN(u1p[p]); }
#pragma unroll
    for (int k = 0; k < HH; ++k) PIN(w1c[k]);
    float bi0 = b0i[c], br0 = b0r[c], bi1 = b1i[c], br1 = b1r[c];
    PIN(bi0); PIN(br0); PIN(bi1); PIN(br1);

    // ---- all 128 tokens of this sequence into 2 VGPRs ----
    const int* xrow = x + b * TT;
    const int tokA = xrow[lane];
    const int tokB = xrow[64 + lane];

    // bperm byte addrs (meaningful on lanes 40..59):
    //  aR: lane 40+j pulls r_j from lane 20+j ; aZ: pulls z_j from lane j
    const int aR = ((lane - 20) & 63) << 2;
    const int aZ = ((lane - 40) & 63) << 2;

    float h0 = 0.f, h1 = 0.f;   // home: lanes 40..59 (unit j at lane 40+j)

    // ---- 2-deep W0 pipeline ----
    const int tok0 = __builtin_amdgcn_readlane(tokA, 0);
    const int tok1 = __builtin_amdgcn_readlane(tokA, 1);
    int tokn2 = __builtin_amdgcn_readlane(tokA, 2);
    float xw_cur = W0[tok0 * H3 + c] + bi0;
    float xw_nxt = W0[tok1 * H3 + c];

#pragma unroll 2
    for (int t = 0; t < TT; ++t) {
        // prefetch: W0 row for t+2 (token staged), token for t+3
        const int t3 = (t + 3 < TT) ? (t + 3) : (TT - 1);
        const float xw_pf = W0[tokn2 * H3 + c];
        const int tokn3 = __builtin_amdgcn_readlane(t3 < 64 ? tokA : tokB, t3 & 63);

        // ---- layer 0: rec0 = h0_staged @ U0 + b0r (LDS broadcast + pk_fma) ----
        const float4* h0q = (const float4*)h0buf;
        v2f a0 = v2f{br0, 0.f};
#pragma unroll
        for (int q = 0; q < 5; ++q) {
            const float4 hv = h0q[q];
            a0 = __builtin_elementwise_fma(v2f{hv.x, hv.y}, u0p[2 * q], a0);
            a0 = __builtin_elementwise_fma(v2f{hv.z, hv.w}, u0p[2 * q + 1], a0);
        }
        const float rec0 = a0.x + a0.y;

        // one sigm -> z (lanes 0-19) and r (lanes 20-39); tanh local on 40-59
        const float sg0 = sigm(xw_cur + rec0);
        const float rv0 = bperm(aR, sg0);
        const float zv0 = bperm(aZ, sg0);
        const float hh0 = tanh_f(xw_cur + rv0 * rec0);
        h0 = fmaf(zv0, h0 - hh0, hh0);                   // lanes 40..59

        // stage h0 for NEXT step's rec0 (off critical path)
        if (lane >= 40 && lane < H3) h0buf[lane - 40] = h0;

        // ---- layer 1: rec1 from staged h1 (LDS); xw1 via readlane (fresh h0) ----
        const float4* h1q = (const float4*)h1buf;
        v2f a1 = v2f{br1, 0.f};
#pragma unroll
        for (int q = 0; q < 5; ++q) {
            const float4 hv = h1q[q];
            a1 = __builtin_elementwise_fma(v2f{hv.x, hv.y}, u1p[2 * q], a1);
            a1 = __builtin_elementwise_fma(v2f{hv.z, hv.w}, u1p[2 * q + 1], a1);
        }
        const float rec1 = a1.x + a1.y;

        float xa = bi1, xb = 0.f;
#pragma unroll
        for (int k = 0; k < 10; ++k) xa = fmaf(bclane(h0, 40 + k), w1c[k], xa);
#pragma unroll
        for (int k = 10; k < HH; ++k) xb = fmaf(bclane(h0, 40 + k), w1c[k], xb);
        const float xw1 = xa + xb;

        const float sg1 = sigm(xw1 + rec1);
        const float rv1 = bperm(aR, sg1);
        const float zv1 = bperm(aZ, sg1);
        const float hh1 = tanh_f(xw1 + rv1 * rec1);
        h1 = fmaf(zv1, h1 - hh1, hh1);

        // stage h1 for next step's rec1 (off critical path)
        if (lane >= 40 && lane < H3) h1buf[lane - 40] = h1;

        // rotate W0 pipeline
        xw_cur = xw_nxt + bi0;
        xw_nxt = xw_pf;
        tokn2 = tokn3;
    }

    // ---- dense (h1 @ Wd + bd) + softmax, lanes 0..14 ----
    const int l = lane < LL ? lane : LL - 1;
    float acc = bd[l];
#pragma unroll
    for (int k = 0; k < HH; ++k)
        acc = fmaf(bclane(h1, 40 + k), Wd[k * LL + l], acc);

    float m = acc;
#pragma unroll
    for (int i = 0; i < LL; ++i) m = fmaxf(m, bclane(acc, i));
    const float e = __expf(acc - m);
    float s = 0.f;
#pragma unroll
    for (int i = 0; i < LL; ++i) s += bclane(e, i);
    const float p = e * fast_rcp(s);

    if (lane < LL) out[b * LL + lane] = p;
}

extern "C" void kernel_launch(void* const* d_in, const int* in_sizes, int n_in,
                              void* d_out, int out_size, void* d_ws, size_t ws_size,
                              hipStream_t stream) {
    const int*   x   = (const int*)  d_in[0];
    const float* W0  = (const float*)d_in[1];
    const float* U0  = (const float*)d_in[2];
    const float* b0i = (const float*)d_in[3];
    const float* b0r = (const float*)d_in[4];
    const float* W1  = (const float*)d_in[5];
    const float* U1  = (const float*)d_in[6];
    const float* b1i = (const float*)d_in[7];
    const float* b1r = (const float*)d_in[8];
    const float* Wd  = (const float*)d_in[9];
    const float* bd  = (const float*)d_in[10];
    // d_in[11] = drop_rate (identity), unused
    float* out = (float*)d_out;

    // 1 batch/wave, 4 waves/block -> 512 blocks = 2 blocks/CU = 2 waves/SIMD.
    dim3 grid(BB / 4), block(256);
    hipLaunchKernelGGL(gru2_kernel, grid, block, 0, stream,
                       x, W0, U0, b0i, b0r, W1, U1, b1i, b1r, Wd, bd, out);
}